// Round 3
// baseline (299.122 us; speedup 1.0000x reference)
//
#include <hip/hip_runtime.h>

typedef _Float16 f16x8 __attribute__((ext_vector_type(8)));
typedef float f32x4 __attribute__((ext_vector_type(4)));

#define CDIM 256
#define NE 1024
#define HW 4096        // H*W
#define CHW 1048576    // C*H*W
#define OUT_COS 262144 // 16*64*256
#define N_PIX 65536
#define NT 32          // 32-code tiles (2 x 16-code subtiles)
#define TAU 0.1f       // margin gate (~14 sigma of screen+quant error)

// ws layout:
//   [0, 512K)      codebook hi fp16, TILED for 16x16x32 B-frags:
//                  addr = t*8192 + sub*4096 + f*512 + q*128 + n*8 + r
//                  code = t*32 + sub*16 + n, dim = f*32 + q*8 + r
//                  (t<32, sub<2, f<8, q<4, n<16, r<8)
//   [512K, 516K)   0.5*||c||^2 fp32
//   [516K, 524K)   0.5*||c||^2 fp64 (exact rescore)

__global__ void prep_kernel(const float* __restrict__ cb,
                            _Float16* __restrict__ hi,
                            float* __restrict__ c2f,
                            double* __restrict__ c2d) {
    int code = blockIdx.x;
    int lane = threadIdx.x; // 64 = 1 wave
    int t = code >> 5, sub = (code >> 4) & 1, n = code & 15;
    const float* row = cb + code * CDIM;
    double s = 0.0;
    #pragma unroll
    for (int i = 0; i < 4; ++i) {
        int d = i * 64 + lane;
        float x = row[d];
        s += (double)x * (double)x;
        int f = d >> 5, q = (d >> 3) & 3, r = d & 7;
        hi[(size_t)t * 8192 + sub * 4096 + f * 512 + q * 128 + n * 8 + r] =
            (_Float16)x;
    }
    #pragma unroll
    for (int off = 32; off > 0; off >>= 1)
        s += __shfl_down(s, off, 64);
    if (lane == 0) { c2f[code] = (float)(0.5 * s); c2d[code] = 0.5 * s; }
}

// Fused z+gt. Grid 512: [0,256)->z, [256,512)->gt. Block = 256 pixels,
// 4 waves x 64 pixels as FOUR 16x16x32 A-tiles.
//
// R3 redesign: NO LDS staging, NO per-tile barriers. The prep kernel's
// tiled fp16 codebook (512 KB, L2-resident) is read as MFMA B-fragments
// DIRECTLY from global (dwordx4, L1/L2-hit). Rationale from R0-R2 PMC:
// duration was flat ~145-165 us across occupancy 17-35% and spill on/off;
// the constant term is the staging pipeline itself -- 2.1M ds_read_b128
// (~41 us of LDS-pipe floor at 12cyc, each B frag feeding only 2 MFMAs)
// plus a vmcnt(0)+lgkmcnt(0) drain every tile in 4-wave lockstep.
// Direct-global B: each frag feeds 4 MFMAs (g=4), B instr traffic halves,
// waves free-run. VGPR demand ~200 fits the 256 cap at 2 waves/SIMD
// (launch_bounds(256,2)); ~50 spare regs give the A-gather load depth.
// Screen = hh-only; per-lane top-2 packed int keys
// (float bits & ~0x3FF | code; s>0 so int order == float order).
// Margin-gated sparse exact rescore (fp64) where top-2 gap < TAU (~0.7%).
__launch_bounds__(256, 2)
__global__ void argmin_kernel(const float* __restrict__ Z,
                              const float* __restrict__ GT,
                              const _Float16* __restrict__ ghi,
                              const float* __restrict__ cb,
                              const float* __restrict__ c2f,
                              const double* __restrict__ c2d,
                              float* __restrict__ out_z,
                              float* __restrict__ out_gt) {
    __shared__ int cand_lds[4][64];                  // per-wave (i1|i2|flag)
    __shared__ float c2s[NE];                        // 0.5*||c||^2, LDS copy
    const int wave = threadIdx.x >> 6;
    const int lane = threadIdx.x & 63;
    const int l15 = lane & 15;
    const int quad = lane >> 4;
    const int half = blockIdx.x >> 8;
    const float* X = half ? GT : Z;
    float* out_idx = half ? out_gt : out_z;
    const int p0 = (blockIdx.x & 255) * 256;

    // preload c2 into LDS (4 KB): per-subtile 16-address gather becomes a
    // broadcast-friendly LDS read off the VMEM critical path
    #pragma unroll
    for (int i = 0; i < 4; ++i)
        c2s[i * 256 + threadIdx.x] = c2f[i * 256 + threadIdx.x];
    __syncthreads(); // the ONLY block-wide barrier

    // ---- A: px-tile g holds pixels p0 + wave*64 + g*16 + l15 (m=l15),
    // k = quad*8 + j per 32-dim frag f (verified R1 A-layout). NEGATED so
    // acc = c2 - hh_dot directly.
    f16x8 nah[4][8];
    #pragma unroll
    for (int g = 0; g < 4; ++g) {
        const int p = p0 + wave * 64 + g * 16 + l15;
        const float* xbase = X + (size_t)(p >> 12) * CHW + (p & 4095);
        #pragma unroll
        for (int f = 0; f < 8; ++f) {
            #pragma unroll
            for (int j = 0; j < 8; ++j) {
                int d = f * 32 + quad * 8 + j;
                nah[g][f][j] = -(_Float16)xbase[(size_t)d * HW];
            }
        }
    }

    int b1[4][4], b2[4][4];
    #pragma unroll
    for (int g = 0; g < 4; ++g)
        #pragma unroll
        for (int r = 0; r < 4; ++r) { b1[g][r] = 0x7fffffff; b2[g][r] = 0x7fffffff; }

    for (int t = 0; t < NT; ++t) {
        #pragma unroll
        for (int sub = 0; sub < 2; ++sub) {
            const int n = t * 32 + sub * 16 + l15; // this lane's code (col)
            const float c2 = c2s[n];
            f32x4 acc[4];
            #pragma unroll
            for (int g = 0; g < 4; ++g)
                acc[g] = (f32x4){c2, c2, c2, c2};

            // B[k=quad*8+j][n=l15]: contiguous 16B/lane straight from the
            // L2-resident tiled codebook. 8 independent loads issued first
            // (in-flight together), then 32 MFMAs consume them.
            f16x8 bh[8];
            const _Float16* bsrc =
                ghi + (size_t)t * 8192 + sub * 4096 + lane * 8;
            #pragma unroll
            for (int f = 0; f < 8; ++f)
                bh[f] = *(const f16x8*)(bsrc + f * 512);

            #pragma unroll
            for (int f = 0; f < 8; ++f) {
                acc[0] = __builtin_amdgcn_mfma_f32_16x16x32_f16(nah[0][f], bh[f], acc[0], 0, 0, 0);
                acc[1] = __builtin_amdgcn_mfma_f32_16x16x32_f16(nah[1][f], bh[f], acc[1], 0, 0, 0);
                acc[2] = __builtin_amdgcn_mfma_f32_16x16x32_f16(nah[2][f], bh[f], acc[2], 0, 0, 0);
                acc[3] = __builtin_amdgcn_mfma_f32_16x16x32_f16(nah[3][f], bh[f], acc[3], 0, 0, 0);
            }

            #pragma unroll
            for (int g = 0; g < 4; ++g) {
                #pragma unroll
                for (int r = 0; r < 4; ++r) {
                    int k = (__float_as_int(acc[g][r]) & 0xFFFFFC00) | n;
                    int mx = max(b1[g][r], k);      // before b1 update!
                    b2[g][r] = min(b2[g][r], mx);
                    b1[g][r] = min(b1[g][r], k);
                }
            }
        }
    }

    // ---- cross-lane top-2 merge: 16 cols live in l15 of each quad ----
    #pragma unroll
    for (int g = 0; g < 4; ++g) {
        #pragma unroll
        for (int r = 0; r < 4; ++r) {
            int x1 = b1[g][r], x2 = b2[g][r];
            #pragma unroll
            for (int off = 8; off > 0; off >>= 1) { // stays in 16-lane group
                int o1 = __shfl_xor(x1, off, 64);
                int o2 = __shfl_xor(x2, off, 64);
                int tt = max(x1, o1);
                x2 = min(min(x2, o2), tt);
                x1 = min(x1, o1);
            }
            if (l15 == 0) {
                const int i1 = x1 & 1023, i2 = x2 & 1023;
                const float s1 = __int_as_float(x1 & 0xFFFFFC00);
                const float s2 = __int_as_float(x2 & 0xFFFFFC00);
                const int row = quad * 4 + r;       // 16x16 C/D row (m89/m91)
                const int slot = g * 16 + row;
                const bool flag = (s2 - s1) < TAU;
                cand_lds[wave][slot] = i1 | (i2 << 10) | (flag ? (1 << 20) : 0);
                if (!flag) out_idx[p0 + wave * 64 + slot] = (float)i1;
            }
        }
    }

    // ---- sparse exact rescore: lane ℓ owns pixel wave*64 + ℓ ----
    // (cand_lds row is written and read by the SAME wave; compiler-inserted
    // lgkmcnt ordering suffices, as verified in R0/R2)
    const int info = cand_lds[wave][lane];
    if (info & (1 << 20)) {
        const int i1 = info & 1023, i2 = (info >> 10) & 1023;
        const int p = p0 + wave * 64 + lane;
        const float* xb = X + (size_t)(p >> 12) * CHW + (p & 4095);
        const float* r1 = cb + (size_t)i1 * CDIM;
        const float* r2 = cb + (size_t)i2 * CDIM;
        double d1 = 0.0, d2 = 0.0;
        #pragma unroll 4
        for (int d = 0; d < CDIM; d += 4) {
            float x0 = xb[(size_t)(d + 0) * HW];
            float x1v = xb[(size_t)(d + 1) * HW];
            float x2v = xb[(size_t)(d + 2) * HW];
            float x3v = xb[(size_t)(d + 3) * HW];
            const float4 v1 = *(const float4*)(r1 + d);
            const float4 v2 = *(const float4*)(r2 + d);
            d1 += (double)x0 * v1.x + (double)x1v * v1.y
                + (double)x2v * v1.z + (double)x3v * v1.w;
            d2 += (double)x0 * v2.x + (double)x1v * v2.y
                + (double)x2v * v2.z + (double)x3v * v2.w;
        }
        const double dd1 = c2d[i1] - d1;
        const double dd2 = c2d[i2] - d2;
        const int bi = (dd2 < dd1 || (dd2 == dd1 && i2 < i1)) ? i2 : i1;
        out_idx[p] = (float)bi;
    }
}

// cosine over H: one block per (b,w), one thread per channel c.
__global__ void cosine_kernel(const float* __restrict__ cb,
                              const float* __restrict__ idx_z_f,
                              const float* __restrict__ idx_gt_f,
                              float* __restrict__ out_cos) {
    __shared__ int s_ig[64], s_iq[64];
    const int bw = blockIdx.x;
    const int c = threadIdx.x;
    const int b = bw >> 6, w = bw & 63;
    if (c < 64) {
        s_ig[c] = (int)idx_gt_f[b * 4096 + c * 64 + w];
    } else if (c < 128) {
        int h = c - 64;
        s_iq[h] = (int)idx_z_f[b * 4096 + h * 64 + w];
    }
    __syncthreads();
    float num = 0.f, sa = 0.f, sb = 0.f;
    #pragma unroll 1
    for (int h = 0; h < 64; h += 4) {
        float av[4], bv[4];
        #pragma unroll
        for (int u = 0; u < 4; ++u) {
            av[u] = cb[s_ig[h + u] * CDIM + c];
            bv[u] = cb[s_iq[h + u] * CDIM + c];
        }
        #pragma unroll
        for (int u = 0; u < 4; ++u) {
            num += av[u] * bv[u];
            sa += av[u] * av[u];
            sb += bv[u] * bv[u];
        }
    }
    const float nx = fmaxf(sqrtf(sa), 1e-8f);
    const float ny = fmaxf(sqrtf(sb), 1e-8f);
    out_cos[bw * CDIM + c] = num / (nx * ny);
}

extern "C" void kernel_launch(void* const* d_in, const int* in_sizes, int n_in,
                              void* d_out, int out_size, void* d_ws, size_t ws_size,
                              hipStream_t stream) {
    const float* z  = (const float*)d_in[0];
    const float* gt = (const float*)d_in[1];
    const float* cb = (const float*)d_in[2];
    float* out = (float*)d_out;

    _Float16* hi = (_Float16*)d_ws;
    float*  c2f = (float*)((char*)d_ws + 512 * 1024);
    double* c2d = (double*)((char*)d_ws + 516 * 1024);

    float* out_cos    = out;                   // (16,64,256)
    float* out_idx_gt = out + OUT_COS;         // (65536,1)
    float* out_idx_z  = out + OUT_COS + N_PIX; // (65536,1)

    prep_kernel<<<NE, 64, 0, stream>>>(cb, hi, c2f, c2d);
    argmin_kernel<<<512, 256, 0, stream>>>(z, gt, hi, cb, c2f, c2d,
                                           out_idx_z, out_idx_gt);
    cosine_kernel<<<1024, 256, 0, stream>>>(cb, out_idx_z, out_idx_gt, out_cos);
}

// Round 4
// 250.147 us; speedup vs baseline: 1.1958x; 1.1958x over previous
//
#include <hip/hip_runtime.h>

typedef _Float16 f16x8 __attribute__((ext_vector_type(8)));
typedef float f32x4 __attribute__((ext_vector_type(4)));

#define CDIM 256
#define NE 1024
#define HW 4096        // H*W
#define CHW 1048576    // C*H*W
#define OUT_COS 262144 // 16*64*256
#define N_PIX 65536
#define NT 32          // 32-code LDS tiles (2 x 16-code subtiles)
#define TAU 0.1f       // margin gate (~14 sigma of screen+quant error)

// ws layout:
//   [0, 512K)      codebook hi fp16, TILED for 16x16x32 B-frags:
//                  addr = t*8192 + sub*4096 + f*512 + q*128 + n*8 + r
//                  code = t*32 + sub*16 + n, dim = f*32 + q*8 + r
//                  (t<32, sub<2, f<8, q<4, n<16, r<8)
//   [512K, 516K)   0.5*||c||^2 fp32
//   [516K, 524K)   0.5*||c||^2 fp64 (exact rescore)

__global__ void prep_kernel(const float* __restrict__ cb,
                            _Float16* __restrict__ hi,
                            float* __restrict__ c2f,
                            double* __restrict__ c2d) {
    int code = blockIdx.x;
    int lane = threadIdx.x; // 64 = 1 wave
    int t = code >> 5, sub = (code >> 4) & 1, n = code & 15;
    const float* row = cb + code * CDIM;
    double s = 0.0;
    #pragma unroll
    for (int i = 0; i < 4; ++i) {
        int d = i * 64 + lane;
        float x = row[d];
        s += (double)x * (double)x;
        int f = d >> 5, q = (d >> 3) & 3, r = d & 7;
        hi[(size_t)t * 8192 + sub * 4096 + f * 512 + q * 128 + n * 8 + r] =
            (_Float16)x;
    }
    #pragma unroll
    for (int off = 32; off > 0; off >>= 1)
        s += __shfl_down(s, off, 64);
    if (lane == 0) { c2f[code] = (float)(0.5 * s); c2d[code] = 0.5 * s; }
}

__device__ __forceinline__ void gl_lds16(const _Float16* g, _Float16* l) {
    __builtin_amdgcn_global_load_lds(
        (const __attribute__((address_space(1))) unsigned int*)g,
        (__attribute__((address_space(3))) unsigned int*)l, 16, 0, 0);
}

// Fused z+gt. Grid 512: [0,256)->z, [256,512)->gt. Block = 256 pixels,
// 4 waves x 64 pixels as FOUR 16x16x32 A-tiles (each B ds_read feeds 4
// MFMAs -- best MFMA:LDS-pipe ratio of R0-R3).
//
// R4 change vs R0: amdgpu_waves_per_eu(2,2). R0's allocator CHOSE 128
// VGPRs (snapping to the 4-waves/EU step) against a ~200-reg live demand
// (nah[4][8]=128 + b1/b2=32 + acc + addressing) -> ~17 MB of scratch
// spill traffic in the inner loop (WRITE_SIZE 18 MB vs 0.6 ideal,
// FETCH_SIZE 171 vs 118 MB). Pinning min=max=2 waves/EU gives the
// allocator the full 256-reg budget with no occupancy incentive to
// shrink: same 2 blocks/CU as R0, zero spill.
// c2 in LDS (R2): acc-init reads don't touch the VMEM queue.
// Screen = hh-only; per-lane top-2 packed int keys
// (float bits & ~0x3FF | code; s>0 so int order == float order).
// Margin-gated sparse exact rescore (fp64) where top-2 gap < TAU (~0.7%).
__attribute__((amdgpu_waves_per_eu(2, 2)))
__launch_bounds__(256)
__global__ void argmin_kernel(const float* __restrict__ Z,
                              const float* __restrict__ GT,
                              const _Float16* __restrict__ ghi,
                              const float* __restrict__ cb,
                              const float* __restrict__ c2f,
                              const double* __restrict__ c2d,
                              float* __restrict__ out_z,
                              float* __restrict__ out_gt) {
    __shared__ __align__(16) _Float16 lbuf[2][8192]; // 2 x 16 KB tiles
    __shared__ int cand_lds[4][64];                  // per-wave (i1|i2|flag)
    __shared__ float c2s[NE];                        // 0.5*||c||^2, LDS copy
    const int wave = threadIdx.x >> 6;
    const int lane = threadIdx.x & 63;
    const int l15 = lane & 15;
    const int quad = lane >> 4;
    const int half = blockIdx.x >> 8;
    const float* X = half ? GT : Z;
    float* out_idx = half ? out_gt : out_z;
    const int p0 = (blockIdx.x & 255) * 256;

    // preload c2 into LDS (4 KB)
    #pragma unroll
    for (int i = 0; i < 4; ++i)
        c2s[i * 256 + threadIdx.x] = c2f[i * 256 + threadIdx.x];

    // ---- A: px-tile g holds pixels p0 + wave*64 + g*16 + l15 (m=l15),
    // k = quad*8 + j per 32-dim frag f (verified R1 A-layout). NEGATED so
    // acc = c2 - hh_dot directly.
    f16x8 nah[4][8];
    #pragma unroll
    for (int g = 0; g < 4; ++g) {
        const int p = p0 + wave * 64 + g * 16 + l15;
        const float* xbase = X + (size_t)(p >> 12) * CHW + (p & 4095);
        #pragma unroll
        for (int f = 0; f < 8; ++f) {
            #pragma unroll
            for (int j = 0; j < 8; ++j) {
                int d = f * 32 + quad * 8 + j;
                nah[g][f][j] = -(_Float16)xbase[(size_t)d * HW];
            }
        }
    }

    int b1[4][4], b2[4][4];
    #pragma unroll
    for (int g = 0; g < 4; ++g)
        #pragma unroll
        for (int r = 0; r < 4; ++r) { b1[g][r] = 0x7fffffff; b2[g][r] = 0x7fffffff; }

    // stage 16 KB tile = 16 x 1KB chunks, 4 per wave
    auto stage = [&](int b, int t) {
        #pragma unroll
        for (int i = 0; i < 4; ++i) {
            const int c = wave * 4 + i;
            gl_lds16(ghi + (size_t)t * 8192 + c * 512 + lane * 8, &lbuf[b][c * 512]);
        }
    };

    stage(0, 0);
    __syncthreads();

    for (int t = 0; t < NT; ++t) {
        const int cur = t & 1;
        if (t < NT - 1) stage(cur ^ 1, t + 1);

        #pragma unroll
        for (int sub = 0; sub < 2; ++sub) {
            const int n = t * 32 + sub * 16 + l15; // this lane's code (col)
            const float c2 = c2s[n];
            f32x4 acc[4];
            #pragma unroll
            for (int g = 0; g < 4; ++g)
                acc[g] = (f32x4){c2, c2, c2, c2};

            #pragma unroll
            for (int f = 0; f < 8; ++f) {
                // B[k=quad*8+j][n=l15]: contiguous 16B/lane, conflict-free
                f16x8 bh = *(const f16x8*)&lbuf[cur][sub * 4096 + f * 512 + lane * 8];
                acc[0] = __builtin_amdgcn_mfma_f32_16x16x32_f16(nah[0][f], bh, acc[0], 0, 0, 0);
                acc[1] = __builtin_amdgcn_mfma_f32_16x16x32_f16(nah[1][f], bh, acc[1], 0, 0, 0);
                acc[2] = __builtin_amdgcn_mfma_f32_16x16x32_f16(nah[2][f], bh, acc[2], 0, 0, 0);
                acc[3] = __builtin_amdgcn_mfma_f32_16x16x32_f16(nah[3][f], bh, acc[3], 0, 0, 0);
            }

            #pragma unroll
            for (int g = 0; g < 4; ++g) {
                #pragma unroll
                for (int r = 0; r < 4; ++r) {
                    int k = (__float_as_int(acc[g][r]) & 0xFFFFFC00) | n;
                    int mx = max(b1[g][r], k);      // before b1 update!
                    b2[g][r] = min(b2[g][r], mx);
                    b1[g][r] = min(b1[g][r], k);
                }
            }
        }
        __syncthreads();
    }

    // ---- cross-lane top-2 merge: 16 cols live in l15 of each quad ----
    #pragma unroll
    for (int g = 0; g < 4; ++g) {
        #pragma unroll
        for (int r = 0; r < 4; ++r) {
            int x1 = b1[g][r], x2 = b2[g][r];
            #pragma unroll
            for (int off = 8; off > 0; off >>= 1) { // stays in 16-lane group
                int o1 = __shfl_xor(x1, off, 64);
                int o2 = __shfl_xor(x2, off, 64);
                int tt = max(x1, o1);
                x2 = min(min(x2, o2), tt);
                x1 = min(x1, o1);
            }
            if (l15 == 0) {
                const int i1 = x1 & 1023, i2 = x2 & 1023;
                const float s1 = __int_as_float(x1 & 0xFFFFFC00);
                const float s2 = __int_as_float(x2 & 0xFFFFFC00);
                const int row = quad * 4 + r;       // 16x16 C/D row (m89/m91)
                const int slot = g * 16 + row;
                const bool flag = (s2 - s1) < TAU;
                cand_lds[wave][slot] = i1 | (i2 << 10) | (flag ? (1 << 20) : 0);
                if (!flag) out_idx[p0 + wave * 64 + slot] = (float)i1;
            }
        }
    }

    // ---- sparse exact rescore: lane ℓ owns pixel wave*64 + ℓ ----
    const int info = cand_lds[wave][lane];
    if (info & (1 << 20)) {
        const int i1 = info & 1023, i2 = (info >> 10) & 1023;
        const int p = p0 + wave * 64 + lane;
        const float* xb = X + (size_t)(p >> 12) * CHW + (p & 4095);
        const float* r1 = cb + (size_t)i1 * CDIM;
        const float* r2 = cb + (size_t)i2 * CDIM;
        double d1 = 0.0, d2 = 0.0;
        #pragma unroll 4
        for (int d = 0; d < CDIM; d += 4) {
            float x0 = xb[(size_t)(d + 0) * HW];
            float x1v = xb[(size_t)(d + 1) * HW];
            float x2v = xb[(size_t)(d + 2) * HW];
            float x3v = xb[(size_t)(d + 3) * HW];
            const float4 v1 = *(const float4*)(r1 + d);
            const float4 v2 = *(const float4*)(r2 + d);
            d1 += (double)x0 * v1.x + (double)x1v * v1.y
                + (double)x2v * v1.z + (double)x3v * v1.w;
            d2 += (double)x0 * v2.x + (double)x1v * v2.y
                + (double)x2v * v2.z + (double)x3v * v2.w;
        }
        const double dd1 = c2d[i1] - d1;
        const double dd2 = c2d[i2] - d2;
        const int bi = (dd2 < dd1 || (dd2 == dd1 && i2 < i1)) ? i2 : i1;
        out_idx[p] = (float)bi;
    }
}

// cosine over H: one block per (b,w), one thread per channel c.
__global__ void cosine_kernel(const float* __restrict__ cb,
                              const float* __restrict__ idx_z_f,
                              const float* __restrict__ idx_gt_f,
                              float* __restrict__ out_cos) {
    __shared__ int s_ig[64], s_iq[64];
    const int bw = blockIdx.x;
    const int c = threadIdx.x;
    const int b = bw >> 6, w = bw & 63;
    if (c < 64) {
        s_ig[c] = (int)idx_gt_f[b * 4096 + c * 64 + w];
    } else if (c < 128) {
        int h = c - 64;
        s_iq[h] = (int)idx_z_f[b * 4096 + h * 64 + w];
    }
    __syncthreads();
    float num = 0.f, sa = 0.f, sb = 0.f;
    #pragma unroll 1
    for (int h = 0; h < 64; h += 4) {
        float av[4], bv[4];
        #pragma unroll
        for (int u = 0; u < 4; ++u) {
            av[u] = cb[s_ig[h + u] * CDIM + c];
            bv[u] = cb[s_iq[h + u] * CDIM + c];
        }
        #pragma unroll
        for (int u = 0; u < 4; ++u) {
            num += av[u] * bv[u];
            sa += av[u] * av[u];
            sb += bv[u] * bv[u];
        }
    }
    const float nx = fmaxf(sqrtf(sa), 1e-8f);
    const float ny = fmaxf(sqrtf(sb), 1e-8f);
    out_cos[bw * CDIM + c] = num / (nx * ny);
}

extern "C" void kernel_launch(void* const* d_in, const int* in_sizes, int n_in,
                              void* d_out, int out_size, void* d_ws, size_t ws_size,
                              hipStream_t stream) {
    const float* z  = (const float*)d_in[0];
    const float* gt = (const float*)d_in[1];
    const float* cb = (const float*)d_in[2];
    float* out = (float*)d_out;

    _Float16* hi = (_Float16*)d_ws;
    float*  c2f = (float*)((char*)d_ws + 512 * 1024);
    double* c2d = (double*)((char*)d_ws + 516 * 1024);

    float* out_cos    = out;                   // (16,64,256)
    float* out_idx_gt = out + OUT_COS;         // (65536,1)
    float* out_idx_z  = out + OUT_COS + N_PIX; // (65536,1)

    prep_kernel<<<NE, 64, 0, stream>>>(cb, hi, c2f, c2d);
    argmin_kernel<<<512, 256, 0, stream>>>(z, gt, hi, cb, c2f, c2d,
                                           out_idx_z, out_idx_gt);
    cosine_kernel<<<1024, 256, 0, stream>>>(cb, out_idx_z, out_idx_gt, out_cos);
}

// Round 5
// 232.524 us; speedup vs baseline: 1.2864x; 1.0758x over previous
//
#include <hip/hip_runtime.h>

typedef _Float16 f16x8 __attribute__((ext_vector_type(8)));
typedef float f32x4 __attribute__((ext_vector_type(4)));

#define CDIM 256
#define NE 1024
#define HW 4096        // H*W
#define CHW 1048576    // C*H*W
#define OUT_COS 262144 // 16*64*256
#define N_PIX 65536
#define NT 32          // 32-code LDS tiles (2 x 16-code subtiles)
#define TAU 0.1f       // margin gate (~14 sigma of screen+quant error)

// x-stage geometry: 8 rounds x 32 dims; row = 256 px fp32 + 16B pad
#define XROW_DW 260          // 1040 B, 16B-aligned
#define XS_DW   (32 * XROW_DW) // 8320 dw = 33280 B per buffer

// ws layout:
//   [0, 512K)      codebook hi fp16, TILED for 16x16x32 B-frags:
//                  addr = t*8192 + sub*4096 + f*512 + q*128 + n*8 + r
//                  code = t*32 + sub*16 + n, dim = f*32 + q*8 + r
//   [512K, 516K)   0.5*||c||^2 fp32
//   [516K, 524K)   0.5*||c||^2 fp64 (exact rescore)

__global__ void prep_kernel(const float* __restrict__ cb,
                            _Float16* __restrict__ hi,
                            float* __restrict__ c2f,
                            double* __restrict__ c2d) {
    int code = blockIdx.x;
    int lane = threadIdx.x; // 64 = 1 wave
    int t = code >> 5, sub = (code >> 4) & 1, n = code & 15;
    const float* row = cb + code * CDIM;
    double s = 0.0;
    #pragma unroll
    for (int i = 0; i < 4; ++i) {
        int d = i * 64 + lane;
        float x = row[d];
        s += (double)x * (double)x;
        int f = d >> 5, q = (d >> 3) & 3, r = d & 7;
        hi[(size_t)t * 8192 + sub * 4096 + f * 512 + q * 128 + n * 8 + r] =
            (_Float16)x;
    }
    #pragma unroll
    for (int off = 32; off > 0; off >>= 1)
        s += __shfl_down(s, off, 64);
    if (lane == 0) { c2f[code] = (float)(0.5 * s); c2d[code] = 0.5 * s; }
}

__device__ __forceinline__ void gl_lds16(const void* g, void* l) {
    __builtin_amdgcn_global_load_lds(
        (const __attribute__((address_space(1))) unsigned int*)g,
        (__attribute__((address_space(3))) unsigned int*)l, 16, 0, 0);
}

// Fused z+gt. Grid 512: [0,256)->z, [256,512)->gt. Block = 256 pixels,
// 4 waves x 64 pixels as FOUR 16x16x32 A-tiles (each B ds_read feeds 4
// MFMAs -- best MFMA:LDS ratio of R0-R4).
//
// R5 change: the A-gather. R0-R4 loaded X as 256 scalar dword HBM loads
// per thread with ~8-deep in-flight (no free VGPRs) -> ~45 us latency-
// throttled phase (guide common-mistake #1). Now: X staged via
// global_load_lds width=16 -- one instr per dim-row covers all 256 block
// pixels (zero dest VGPRs, full vmcnt depth, HBM BW-bound ~25 us) -- in
// 8 double-buffered rounds of 32 dims; nah rebuilt from LDS by
// ds_read_b32 with immediate offsets (4-way bank alias = 1.58x, cheap).
// lbuf aliases the dead x-stage buffers: LDS 70 KB, 2 blocks/CU.
// Round loop fully unrolled so nah[g][f] is statically indexed (rule #20).
// Main loop / screen / rescore unchanged from R4.
__launch_bounds__(256, 2)
__global__ void argmin_kernel(const float* __restrict__ Z,
                              const float* __restrict__ GT,
                              const _Float16* __restrict__ ghi,
                              const float* __restrict__ cb,
                              const float* __restrict__ c2f,
                              const double* __restrict__ c2d,
                              float* __restrict__ out_z,
                              float* __restrict__ out_gt) {
    __shared__ __align__(16) char smem[2 * 33280 + 4096 + 1024];
    float*    xs   = (float*)smem;              // 2 x 33280 B (A-phase)
    _Float16* lbuf = (_Float16*)smem;           // 2 x 16 KB (main loop, alias)
    float*    c2s  = (float*)(smem + 66560);    // 4 KB
    int*      cand = (int*)(smem + 70656);      // 4 waves x 64

    const int wave = threadIdx.x >> 6;
    const int lane = threadIdx.x & 63;
    const int l15 = lane & 15;
    const int quad = lane >> 4;
    const int half = blockIdx.x >> 8;
    const float* X = half ? GT : Z;
    float* out_idx = half ? out_gt : out_z;
    const int p0 = (blockIdx.x & 255) * 256;

    // preload c2 into LDS (4 KB); ordered before first use by A-phase syncs
    #pragma unroll
    for (int i = 0; i < 4; ++i)
        c2s[i * 256 + threadIdx.x] = c2f[i * 256 + threadIdx.x];

    // ---- A-phase: stage 32-dim rounds of X into LDS, rebuild nah ----
    // pixel block is 4096-aligned-safe: p0..p0+255 within one batch image
    const float* xsrc = X + (size_t)(p0 >> 12) * CHW + (p0 & 4095);

    auto stage_x = [&](int b, int fr) {
        #pragma unroll
        for (int i = 0; i < 8; ++i) {
            const int row = wave * 8 + i;          // lds row (= d & 31)
            const int d = fr * 32 + row;           // global dim
            gl_lds16(xsrc + (size_t)d * HW + lane * 4,
                     xs + b * XS_DW + row * XROW_DW);
        }
    };

    f16x8 nah[4][8];
    stage_x(0, 0);
    int xb = 0;
    #pragma unroll
    for (int f = 0; f < 8; ++f) {
        __syncthreads();                 // xs[xb] ready (drains vmcnt)
        if (f < 7) stage_x(xb ^ 1, f + 1);
        // rebuild nah[g][f]: d = f*32 + quad*8 + j at px = wave*64+g*16+l15
        const float* xsb = xs + xb * XS_DW;
        const int abase = quad * 8 * XROW_DW + wave * 64 + l15;
        #pragma unroll
        for (int g = 0; g < 4; ++g) {
            f16x8 t;
            #pragma unroll
            for (int j = 0; j < 8; ++j)
                t[j] = -(_Float16)xsb[abase + j * XROW_DW + g * 16];
            nah[g][f] = t;
        }
        xb ^= 1;
    }
    __syncthreads(); // all rebuilds done before lbuf overwrites xs

    int b1[4][4], b2[4][4];
    #pragma unroll
    for (int g = 0; g < 4; ++g)
        #pragma unroll
        for (int r = 0; r < 4; ++r) { b1[g][r] = 0x7fffffff; b2[g][r] = 0x7fffffff; }

    // stage 16 KB B-tile = 16 x 1KB chunks, 4 per wave
    auto stage = [&](int b, int t) {
        #pragma unroll
        for (int i = 0; i < 4; ++i) {
            const int c = wave * 4 + i;
            gl_lds16(ghi + (size_t)t * 8192 + c * 512 + lane * 8,
                     lbuf + b * 8192 + c * 512);
        }
    };

    stage(0, 0);
    __syncthreads();

    for (int t = 0; t < NT; ++t) {
        const int cur = t & 1;
        if (t < NT - 1) stage(cur ^ 1, t + 1);

        #pragma unroll
        for (int sub = 0; sub < 2; ++sub) {
            const int n = t * 32 + sub * 16 + l15; // this lane's code (col)
            const float c2 = c2s[n];
            f32x4 acc[4];
            #pragma unroll
            for (int g = 0; g < 4; ++g)
                acc[g] = (f32x4){c2, c2, c2, c2};

            #pragma unroll
            for (int f = 0; f < 8; ++f) {
                // B[k=quad*8+j][n=l15]: contiguous 16B/lane, conflict-free
                f16x8 bh = *(const f16x8*)&lbuf[cur * 8192 + sub * 4096 + f * 512 + lane * 8];
                acc[0] = __builtin_amdgcn_mfma_f32_16x16x32_f16(nah[0][f], bh, acc[0], 0, 0, 0);
                acc[1] = __builtin_amdgcn_mfma_f32_16x16x32_f16(nah[1][f], bh, acc[1], 0, 0, 0);
                acc[2] = __builtin_amdgcn_mfma_f32_16x16x32_f16(nah[2][f], bh, acc[2], 0, 0, 0);
                acc[3] = __builtin_amdgcn_mfma_f32_16x16x32_f16(nah[3][f], bh, acc[3], 0, 0, 0);
            }

            #pragma unroll
            for (int g = 0; g < 4; ++g) {
                #pragma unroll
                for (int r = 0; r < 4; ++r) {
                    int k = (__float_as_int(acc[g][r]) & 0xFFFFFC00) | n;
                    int mx = max(b1[g][r], k);      // before b1 update!
                    b2[g][r] = min(b2[g][r], mx);
                    b1[g][r] = min(b1[g][r], k);
                }
            }
        }
        __syncthreads();
    }

    // ---- cross-lane top-2 merge: 16 cols live in l15 of each quad ----
    #pragma unroll
    for (int g = 0; g < 4; ++g) {
        #pragma unroll
        for (int r = 0; r < 4; ++r) {
            int x1 = b1[g][r], x2 = b2[g][r];
            #pragma unroll
            for (int off = 8; off > 0; off >>= 1) { // stays in 16-lane group
                int o1 = __shfl_xor(x1, off, 64);
                int o2 = __shfl_xor(x2, off, 64);
                int tt = max(x1, o1);
                x2 = min(min(x2, o2), tt);
                x1 = min(x1, o1);
            }
            if (l15 == 0) {
                const int i1 = x1 & 1023, i2 = x2 & 1023;
                const float s1 = __int_as_float(x1 & 0xFFFFFC00);
                const float s2 = __int_as_float(x2 & 0xFFFFFC00);
                const int row = quad * 4 + r;       // 16x16 C/D row (m89/m91)
                const int slot = g * 16 + row;
                const bool flag = (s2 - s1) < TAU;
                cand[wave * 64 + slot] = i1 | (i2 << 10) | (flag ? (1 << 20) : 0);
                if (!flag) out_idx[p0 + wave * 64 + slot] = (float)i1;
            }
        }
    }

    // ---- sparse exact rescore: lane ℓ owns pixel wave*64 + ℓ ----
    // (cand row is written and read by the SAME wave; compiler-inserted
    // lgkmcnt ordering suffices, as verified in R0/R2/R4)
    const int info = cand[wave * 64 + lane];
    if (info & (1 << 20)) {
        const int i1 = info & 1023, i2 = (info >> 10) & 1023;
        const int p = p0 + wave * 64 + lane;
        const float* xb2 = X + (size_t)(p >> 12) * CHW + (p & 4095);
        const float* r1 = cb + (size_t)i1 * CDIM;
        const float* r2 = cb + (size_t)i2 * CDIM;
        double d1 = 0.0, d2 = 0.0;
        #pragma unroll 4
        for (int d = 0; d < CDIM; d += 4) {
            float x0 = xb2[(size_t)(d + 0) * HW];
            float x1v = xb2[(size_t)(d + 1) * HW];
            float x2v = xb2[(size_t)(d + 2) * HW];
            float x3v = xb2[(size_t)(d + 3) * HW];
            const float4 v1 = *(const float4*)(r1 + d);
            const float4 v2 = *(const float4*)(r2 + d);
            d1 += (double)x0 * v1.x + (double)x1v * v1.y
                + (double)x2v * v1.z + (double)x3v * v1.w;
            d2 += (double)x0 * v2.x + (double)x1v * v2.y
                + (double)x2v * v2.z + (double)x3v * v2.w;
        }
        const double dd1 = c2d[i1] - d1;
        const double dd2 = c2d[i2] - d2;
        const int bi = (dd2 < dd1 || (dd2 == dd1 && i2 < i1)) ? i2 : i1;
        out_idx[p] = (float)bi;
    }
}

// cosine over H: one block per (b,w), one thread per channel c.
__global__ void cosine_kernel(const float* __restrict__ cb,
                              const float* __restrict__ idx_z_f,
                              const float* __restrict__ idx_gt_f,
                              float* __restrict__ out_cos) {
    __shared__ int s_ig[64], s_iq[64];
    const int bw = blockIdx.x;
    const int c = threadIdx.x;
    const int b = bw >> 6, w = bw & 63;
    if (c < 64) {
        s_ig[c] = (int)idx_gt_f[b * 4096 + c * 64 + w];
    } else if (c < 128) {
        int h = c - 64;
        s_iq[h] = (int)idx_z_f[b * 4096 + h * 64 + w];
    }
    __syncthreads();
    float num = 0.f, sa = 0.f, sb = 0.f;
    #pragma unroll 1
    for (int h = 0; h < 64; h += 4) {
        float av[4], bv[4];
        #pragma unroll
        for (int u = 0; u < 4; ++u) {
            av[u] = cb[s_ig[h + u] * CDIM + c];
            bv[u] = cb[s_iq[h + u] * CDIM + c];
        }
        #pragma unroll
        for (int u = 0; u < 4; ++u) {
            num += av[u] * bv[u];
            sa += av[u] * av[u];
            sb += bv[u] * bv[u];
        }
    }
    const float nx = fmaxf(sqrtf(sa), 1e-8f);
    const float ny = fmaxf(sqrtf(sb), 1e-8f);
    out_cos[bw * CDIM + c] = num / (nx * ny);
}

extern "C" void kernel_launch(void* const* d_in, const int* in_sizes, int n_in,
                              void* d_out, int out_size, void* d_ws, size_t ws_size,
                              hipStream_t stream) {
    const float* z  = (const float*)d_in[0];
    const float* gt = (const float*)d_in[1];
    const float* cb = (const float*)d_in[2];
    float* out = (float*)d_out;

    _Float16* hi = (_Float16*)d_ws;
    float*  c2f = (float*)((char*)d_ws + 512 * 1024);
    double* c2d = (double*)((char*)d_ws + 516 * 1024);

    float* out_cos    = out;                   // (16,64,256)
    float* out_idx_gt = out + OUT_COS;         // (65536,1)
    float* out_idx_z  = out + OUT_COS + N_PIX; // (65536,1)

    prep_kernel<<<NE, 64, 0, stream>>>(cb, hi, c2f, c2d);
    argmin_kernel<<<512, 256, 0, stream>>>(z, gt, hi, cb, c2f, c2d,
                                           out_idx_z, out_idx_gt);
    cosine_kernel<<<1024, 256, 0, stream>>>(cb, out_idx_z, out_idx_gt, out_cos);
}

// Round 6
// 229.012 us; speedup vs baseline: 1.3061x; 1.0153x over previous
//
#include <hip/hip_runtime.h>

typedef _Float16 f16x8 __attribute__((ext_vector_type(8)));
typedef float f32x4 __attribute__((ext_vector_type(4)));

#define CDIM 256
#define NE 1024
#define HW 4096        // H*W
#define CHW 1048576    // C*H*W
#define OUT_COS 262144 // 16*64*256
#define N_PIX 65536
#define NT 32          // 32-code LDS tiles (2 x 16-code subtiles)
#define TAU 0.1f       // margin gate (~14 sigma of screen+quant error)

// x-stage geometry: 16 rounds x 16 dims; row = 256 px fp32 + 16B pad
#define XROW_DW 260            // 1040 B, 16B-aligned
#define XS_DW   (16 * XROW_DW) // 4160 dw = 16640 B per buffer

// ws layout:
//   [0, 512K)      codebook hi fp16, TILED for 16x16x32 B-frags:
//                  addr = t*8192 + sub*4096 + f*512 + q*128 + n*8 + r
//                  code = t*32 + sub*16 + n, dim = f*32 + q*8 + r
//   [512K, 516K)   0.5*||c||^2 fp32
//   [516K, 524K)   0.5*||c||^2 fp64 (exact rescore)

__global__ void prep_kernel(const float* __restrict__ cb,
                            _Float16* __restrict__ hi,
                            float* __restrict__ c2f,
                            double* __restrict__ c2d) {
    int code = blockIdx.x;
    int lane = threadIdx.x; // 64 = 1 wave
    int t = code >> 5, sub = (code >> 4) & 1, n = code & 15;
    const float* row = cb + code * CDIM;
    double s = 0.0;
    #pragma unroll
    for (int i = 0; i < 4; ++i) {
        int d = i * 64 + lane;
        float x = row[d];
        s += (double)x * (double)x;
        int f = d >> 5, q = (d >> 3) & 3, r = d & 7;
        hi[(size_t)t * 8192 + sub * 4096 + f * 512 + q * 128 + n * 8 + r] =
            (_Float16)x;
    }
    #pragma unroll
    for (int off = 32; off > 0; off >>= 1)
        s += __shfl_down(s, off, 64);
    if (lane == 0) { c2f[code] = (float)(0.5 * s); c2d[code] = 0.5 * s; }
}

__device__ __forceinline__ void gl_lds16(const void* g, void* l) {
    __builtin_amdgcn_global_load_lds(
        (const __attribute__((address_space(1))) unsigned int*)g,
        (__attribute__((address_space(3))) unsigned int*)l, 16, 0, 0);
}

// Fused z+gt. Grid 512: [0,256)->z, [256,512)->gt. Block = 256 pixels,
// 4 waves x 64 pixels as FOUR 16x16x32 A-tiles (each B ds_read feeds 4
// MFMAs).
//
// R6 change: LDS footprint. R5's 2x33KB A-stage dbuf made LDS 71.7 KB ->
// 2 blocks/CU, the sole occupancy limiter (VGPR=112 allows 4 waves/SIMD).
// Now A-phase stages 16 rounds x 16 dims: xs dbuf = 2x16.6 KB, aliased by
// the 32 KB main-loop lbuf; total LDS 38.4 KB -> 4 blocks/CU, 16 waves/CU.
// Bonus: per-round rebuild activates 2 of 4 quads (32 lanes / 16 banks =
// 2-way = free) so R5's 1M bank conflicts drop too.
// A-gather stays global_load_lds width=16 (R5's win: zero dest VGPRs, one
// instr covers all 256 block px per dim-row, no spill: WRITE 22.6->0.64MB).
// Screen = hh-only; per-lane top-2 packed int keys
// (float bits & ~0x3FF | code; s>0 so int order == float order).
// Margin-gated sparse exact rescore (fp64) where top-2 gap < TAU (~0.7%).
__launch_bounds__(256, 2)
__global__ void argmin_kernel(const float* __restrict__ Z,
                              const float* __restrict__ GT,
                              const _Float16* __restrict__ ghi,
                              const float* __restrict__ cb,
                              const float* __restrict__ c2f,
                              const double* __restrict__ c2d,
                              float* __restrict__ out_z,
                              float* __restrict__ out_gt) {
    __shared__ __align__(16) char smem[2 * 16640 + 4096 + 1024];
    float*    xs   = (float*)smem;              // 2 x 16640 B (A-phase)
    _Float16* lbuf = (_Float16*)smem;           // 2 x 16 KB (main loop, alias)
    float*    c2s  = (float*)(smem + 33280);    // 4 KB
    int*      cand = (int*)(smem + 37376);      // 4 waves x 64

    const int wave = threadIdx.x >> 6;
    const int lane = threadIdx.x & 63;
    const int l15 = lane & 15;
    const int quad = lane >> 4;
    const int half = blockIdx.x >> 8;
    const float* X = half ? GT : Z;
    float* out_idx = half ? out_gt : out_z;
    const int p0 = (blockIdx.x & 255) * 256;

    // preload c2 into LDS (4 KB); ordered before first use by A-phase syncs
    #pragma unroll
    for (int i = 0; i < 4; ++i)
        c2s[i * 256 + threadIdx.x] = c2f[i * 256 + threadIdx.x];

    // ---- A-phase: stage 16-dim rounds of X into LDS, rebuild nah ----
    const float* xsrc = X + (size_t)(p0 >> 12) * CHW + (p0 & 4095);

    // round fr stages dims [fr*16, fr*16+16); row rr <- dim fr*16+rr
    auto stage_x = [&](int b, int fr) {
        #pragma unroll
        for (int i = 0; i < 4; ++i) {
            const int rr = wave * 4 + i;
            const int d = fr * 16 + rr;
            gl_lds16(xsrc + (size_t)d * HW + lane * 4,
                     xs + b * XS_DW + rr * XROW_DW);
        }
    };

    // rebuild: lane's dims for frag f are d = f*32 + quad*8 + j, j<8.
    // round fr = 2f + (quad>>1) holds them at rr = (quad&1)*8 + j.
    f16x8 nah[4][8];
    stage_x(0, 0);
    int xb = 0;
    #pragma unroll
    for (int fr = 0; fr < 16; ++fr) {
        __syncthreads();                 // xs[xb] ready (drains vmcnt)
        if (fr < 15) stage_x(xb ^ 1, fr + 1);
        if ((quad >> 1) == (fr & 1)) {
            const int f = fr >> 1;       // static after unroll (rule #20)
            const float* xsb = xs + xb * XS_DW;
            const int abase = (quad & 1) * 8 * XROW_DW + wave * 64 + l15;
            #pragma unroll
            for (int g = 0; g < 4; ++g) {
                f16x8 tv;
                #pragma unroll
                for (int j = 0; j < 8; ++j)
                    tv[j] = -(_Float16)xsb[abase + j * XROW_DW + g * 16];
                nah[g][f] = tv;
            }
        }
        xb ^= 1;
    }
    __syncthreads(); // all rebuilds done before lbuf overwrites xs

    int b1[4][4], b2[4][4];
    #pragma unroll
    for (int g = 0; g < 4; ++g)
        #pragma unroll
        for (int r = 0; r < 4; ++r) { b1[g][r] = 0x7fffffff; b2[g][r] = 0x7fffffff; }

    // stage 16 KB B-tile = 16 x 1KB chunks, 4 per wave
    auto stage = [&](int b, int t) {
        #pragma unroll
        for (int i = 0; i < 4; ++i) {
            const int c = wave * 4 + i;
            gl_lds16(ghi + (size_t)t * 8192 + c * 512 + lane * 8,
                     lbuf + b * 8192 + c * 512);
        }
    };

    stage(0, 0);
    __syncthreads();

    for (int t = 0; t < NT; ++t) {
        const int cur = t & 1;
        if (t < NT - 1) stage(cur ^ 1, t + 1);

        #pragma unroll
        for (int sub = 0; sub < 2; ++sub) {
            const int n = t * 32 + sub * 16 + l15; // this lane's code (col)
            const float c2 = c2s[n];
            f32x4 acc[4];
            #pragma unroll
            for (int g = 0; g < 4; ++g)
                acc[g] = (f32x4){c2, c2, c2, c2};

            #pragma unroll
            for (int f = 0; f < 8; ++f) {
                // B[k=quad*8+j][n=l15]: contiguous 16B/lane, conflict-free
                f16x8 bh = *(const f16x8*)&lbuf[cur * 8192 + sub * 4096 + f * 512 + lane * 8];
                acc[0] = __builtin_amdgcn_mfma_f32_16x16x32_f16(nah[0][f], bh, acc[0], 0, 0, 0);
                acc[1] = __builtin_amdgcn_mfma_f32_16x16x32_f16(nah[1][f], bh, acc[1], 0, 0, 0);
                acc[2] = __builtin_amdgcn_mfma_f32_16x16x32_f16(nah[2][f], bh, acc[2], 0, 0, 0);
                acc[3] = __builtin_amdgcn_mfma_f32_16x16x32_f16(nah[3][f], bh, acc[3], 0, 0, 0);
            }

            #pragma unroll
            for (int g = 0; g < 4; ++g) {
                #pragma unroll
                for (int r = 0; r < 4; ++r) {
                    int k = (__float_as_int(acc[g][r]) & 0xFFFFFC00) | n;
                    int mx = max(b1[g][r], k);      // before b1 update!
                    b2[g][r] = min(b2[g][r], mx);
                    b1[g][r] = min(b1[g][r], k);
                }
            }
        }
        __syncthreads();
    }

    // ---- cross-lane top-2 merge: 16 cols live in l15 of each quad ----
    #pragma unroll
    for (int g = 0; g < 4; ++g) {
        #pragma unroll
        for (int r = 0; r < 4; ++r) {
            int x1 = b1[g][r], x2 = b2[g][r];
            #pragma unroll
            for (int off = 8; off > 0; off >>= 1) { // stays in 16-lane group
                int o1 = __shfl_xor(x1, off, 64);
                int o2 = __shfl_xor(x2, off, 64);
                int tt = max(x1, o1);
                x2 = min(min(x2, o2), tt);
                x1 = min(x1, o1);
            }
            if (l15 == 0) {
                const int i1 = x1 & 1023, i2 = x2 & 1023;
                const float s1 = __int_as_float(x1 & 0xFFFFFC00);
                const float s2 = __int_as_float(x2 & 0xFFFFFC00);
                const int row = quad * 4 + r;       // 16x16 C/D row (m89/m91)
                const int slot = g * 16 + row;
                const bool flag = (s2 - s1) < TAU;
                cand[wave * 64 + slot] = i1 | (i2 << 10) | (flag ? (1 << 20) : 0);
                if (!flag) out_idx[p0 + wave * 64 + slot] = (float)i1;
            }
        }
    }

    // ---- sparse exact rescore: lane ℓ owns pixel wave*64 + ℓ ----
    // (cand row is written and read by the SAME wave; compiler-inserted
    // lgkmcnt ordering suffices, as verified in R0/R2/R4/R5)
    const int info = cand[wave * 64 + lane];
    if (info & (1 << 20)) {
        const int i1 = info & 1023, i2 = (info >> 10) & 1023;
        const int p = p0 + wave * 64 + lane;
        const float* xb2 = X + (size_t)(p >> 12) * CHW + (p & 4095);
        const float* r1 = cb + (size_t)i1 * CDIM;
        const float* r2 = cb + (size_t)i2 * CDIM;
        double d1 = 0.0, d2 = 0.0;
        #pragma unroll 4
        for (int d = 0; d < CDIM; d += 4) {
            float x0 = xb2[(size_t)(d + 0) * HW];
            float x1v = xb2[(size_t)(d + 1) * HW];
            float x2v = xb2[(size_t)(d + 2) * HW];
            float x3v = xb2[(size_t)(d + 3) * HW];
            const float4 v1 = *(const float4*)(r1 + d);
            const float4 v2 = *(const float4*)(r2 + d);
            d1 += (double)x0 * v1.x + (double)x1v * v1.y
                + (double)x2v * v1.z + (double)x3v * v1.w;
            d2 += (double)x0 * v2.x + (double)x1v * v2.y
                + (double)x2v * v2.z + (double)x3v * v2.w;
        }
        const double dd1 = c2d[i1] - d1;
        const double dd2 = c2d[i2] - d2;
        const int bi = (dd2 < dd1 || (dd2 == dd1 && i2 < i1)) ? i2 : i1;
        out_idx[p] = (float)bi;
    }
}

// cosine over H: one block per (b,w), one thread per channel c.
__global__ void cosine_kernel(const float* __restrict__ cb,
                              const float* __restrict__ idx_z_f,
                              const float* __restrict__ idx_gt_f,
                              float* __restrict__ out_cos) {
    __shared__ int s_ig[64], s_iq[64];
    const int bw = blockIdx.x;
    const int c = threadIdx.x;
    const int b = bw >> 6, w = bw & 63;
    if (c < 64) {
        s_ig[c] = (int)idx_gt_f[b * 4096 + c * 64 + w];
    } else if (c < 128) {
        int h = c - 64;
        s_iq[h] = (int)idx_z_f[b * 4096 + h * 64 + w];
    }
    __syncthreads();
    float num = 0.f, sa = 0.f, sb = 0.f;
    #pragma unroll 1
    for (int h = 0; h < 64; h += 4) {
        float av[4], bv[4];
        #pragma unroll
        for (int u = 0; u < 4; ++u) {
            av[u] = cb[s_ig[h + u] * CDIM + c];
            bv[u] = cb[s_iq[h + u] * CDIM + c];
        }
        #pragma unroll
        for (int u = 0; u < 4; ++u) {
            num += av[u] * bv[u];
            sa += av[u] * av[u];
            sb += bv[u] * bv[u];
        }
    }
    const float nx = fmaxf(sqrtf(sa), 1e-8f);
    const float ny = fmaxf(sqrtf(sb), 1e-8f);
    out_cos[bw * CDIM + c] = num / (nx * ny);
}

extern "C" void kernel_launch(void* const* d_in, const int* in_sizes, int n_in,
                              void* d_out, int out_size, void* d_ws, size_t ws_size,
                              hipStream_t stream) {
    const float* z  = (const float*)d_in[0];
    const float* gt = (const float*)d_in[1];
    const float* cb = (const float*)d_in[2];
    float* out = (float*)d_out;

    _Float16* hi = (_Float16*)d_ws;
    float*  c2f = (float*)((char*)d_ws + 512 * 1024);
    double* c2d = (double*)((char*)d_ws + 516 * 1024);

    float* out_cos    = out;                   // (16,64,256)
    float* out_idx_gt = out + OUT_COS;         // (65536,1)
    float* out_idx_z  = out + OUT_COS + N_PIX; // (65536,1)

    prep_kernel<<<NE, 64, 0, stream>>>(cb, hi, c2f, c2d);
    argmin_kernel<<<512, 256, 0, stream>>>(z, gt, hi, cb, c2f, c2d,
                                           out_idx_z, out_idx_gt);
    cosine_kernel<<<1024, 256, 0, stream>>>(cb, out_idx_z, out_idx_gt, out_cos);
}